// Round 3
// baseline (1661.810 us; speedup 1.0000x reference)
//
#include <hip/hip_runtime.h>
#include <math.h>

// ODE-RNN encoder, fully fused: one 64-lane wave per batch sample.
// Lane j owns hidden-unit j of the 64-wide MLP layers; weights live in
// registers for the entire 256-step sequence. ODE state y and Tsit5 k's are
// replicated across lanes (lane j holds component j&15), so stage blends and
// the error estimate are pure-register VALU work. Cross-lane: LDS broadcast
// float4 reads (uniform addr = free) + shfl_xor reductions.
// Latency cuts: x_seq prefetched to LDS (off the serial chain),
// v_rcp_f32 in tanh/sigmoid, exp2/log2 instead of powf.

namespace {
constexpr int LSEQ = 256;

typedef float f32x2 __attribute__((ext_vector_type(2)));

__device__ __forceinline__ f32x2 mk2(float a, float b) {
    f32x2 r; r.x = a; r.y = b; return r;
}
__device__ __forceinline__ f32x2 fma2(f32x2 a, f32x2 b, f32x2 c) {
    return __builtin_elementwise_fma(a, b, c);
}

__device__ __forceinline__ float tanh_f(float x) {
    // tanh(x) = 1 - 2/(exp2(2*log2e*x)+1); saturates correctly at +-inf
    float e = exp2f(x * 2.8853900817779268f);
    return 1.0f - 2.0f * __builtin_amdgcn_rcpf(e + 1.0f);
}
__device__ __forceinline__ float sigm_f(float x) {
    return __builtin_amdgcn_rcpf(1.0f + exp2f(x * -1.4426950408889634f));
}
} // namespace

extern "C" __global__ void __launch_bounds__(64, 1)
odern_kernel(const float* __restrict__ x_seq,
             const float* __restrict__ W0, const float* __restrict__ b0,
             const float* __restrict__ W1, const float* __restrict__ b1,
             const float* __restrict__ W2, const float* __restrict__ b2,
             const float* __restrict__ W3, const float* __restrict__ b3,
             const float* __restrict__ Wih, const float* __restrict__ Whh,
             const float* __restrict__ bih, const float* __restrict__ bn,
             const float* __restrict__ Wp, const float* __restrict__ bp,
             float* __restrict__ out)
{
    const int j   = threadIdx.x;      // 0..63
    const int b   = blockIdx.x;       // sample
    const int i16 = j & 15;           // owned y-component (replicated x4)

    __shared__ __align__(16) float s_in[16];   // MLP stage input broadcast
    __shared__ __align__(16) float s_hA[64];   // hidden broadcast (ping)
    __shared__ __align__(16) float s_hB[64];   // hidden broadcast (pong)
    __shared__ __align__(16) float s_x[2 * LSEQ];  // this sample's input row
    __shared__ float s_ig[48];
    __shared__ float s_hg[48];

    // ---------------- x row -> LDS (once; off the serial chain) -------
    {
        const float4* xv = (const float4*)(x_seq + (long)b * (2 * LSEQ));
        float4 t0 = xv[j];
        float4 t1 = xv[j + 64];
        ((float4*)s_x)[j]      = t0;
        ((float4*)s_x)[j + 64] = t1;
    }

    // ---------------- weights -> registers (once) ----------------
    f32x2 w0v[8], w1v[32], w2v[32], w3v[8], whv[8];
    {
        const float4* p = (const float4*)(W0 + j * 16);
        #pragma unroll
        for (int q = 0; q < 4; ++q) { float4 u = p[q];
            w0v[2*q] = mk2(u.x, u.y); w0v[2*q+1] = mk2(u.z, u.w); }
    }
    {
        const float4* p = (const float4*)(W1 + j * 64);
        #pragma unroll
        for (int q = 0; q < 16; ++q) { float4 u = p[q];
            w1v[2*q] = mk2(u.x, u.y); w1v[2*q+1] = mk2(u.z, u.w); }
    }
    {
        const float4* p = (const float4*)(W2 + j * 64);
        #pragma unroll
        for (int q = 0; q < 16; ++q) { float4 u = p[q];
            w2v[2*q] = mk2(u.x, u.y); w2v[2*q+1] = mk2(u.z, u.w); }
    }
    {
        // lane j computes partial of out[i16] over k in [16*(j>>4), +16)
        const float4* p = (const float4*)(W3 + i16 * 64 + (j >> 4) * 16);
        #pragma unroll
        for (int q = 0; q < 4; ++q) { float4 u = p[q];
            w3v[2*q] = mk2(u.x, u.y); w3v[2*q+1] = mk2(u.z, u.w); }
    }
    const int jg = (j < 48) ? j : 47;   // clamp for 48-row GRU mats
    {
        const float4* p = (const float4*)(Whh + jg * 16);
        #pragma unroll
        for (int q = 0; q < 4; ++q) { float4 u = p[q];
            whv[2*q] = mk2(u.x, u.y); whv[2*q+1] = mk2(u.z, u.w); }
    }
    const float wih0 = Wih[jg * 2], wih1 = Wih[jg * 2 + 1], bihj = bih[jg];
    const float bs0 = b0[j], bs1 = b1[j], bs2 = b2[j];
    const float b3r = b3[i16], bnr = bn[i16], wpr = Wp[i16];
    __syncthreads();   // s_x visible before the sequence loop

    // 64-wide dot: 4 packed accumulators, chain length 8
    auto dot64 = [&](const float4* p4, const f32x2* wv, float bias) -> float {
        f32x2 a0 = mk2(bias, 0.f), a1 = mk2(0.f, 0.f),
              a2 = mk2(0.f, 0.f),  a3 = mk2(0.f, 0.f);
        #pragma unroll
        for (int q = 0; q < 16; q += 2) {
            float4 u = p4[q];
            a0 = fma2(wv[2*q],   mk2(u.x, u.y), a0);
            a1 = fma2(wv[2*q+1], mk2(u.z, u.w), a1);
            float4 v = p4[q+1];
            a2 = fma2(wv[2*q+2], mk2(v.x, v.y), a2);
            a3 = fma2(wv[2*q+3], mk2(v.z, v.w), a3);
        }
        f32x2 s = (a0 + a1) + (a2 + a3);
        return s.x + s.y;
    };
    // 16-wide dot: 2 packed accumulators, chain length 4
    auto dot16 = [&](const float4* p4, const f32x2* wv, float bias) -> float {
        f32x2 a0 = mk2(bias, 0.f), a1 = mk2(0.f, 0.f);
        float4 u = p4[0];
        a0 = fma2(wv[0], mk2(u.x, u.y), a0);
        a1 = fma2(wv[1], mk2(u.z, u.w), a1);
        float4 v = p4[1];
        a0 = fma2(wv[2], mk2(v.x, v.y), a0);
        a1 = fma2(wv[3], mk2(v.z, v.w), a1);
        float4 w = p4[2];
        a0 = fma2(wv[4], mk2(w.x, w.y), a0);
        a1 = fma2(wv[5], mk2(w.z, w.w), a1);
        float4 z = p4[3];
        a0 = fma2(wv[6], mk2(z.x, z.y), a0);
        a1 = fma2(wv[7], mk2(z.z, z.w), a1);
        f32x2 s = a0 + a1;
        return s.x + s.y;
    };

    // MLP eval: input = lane-replicated ys (component i16); returns replicated out component.
    auto mlp = [&](float ys) -> float {
        if (j < 16) s_in[j] = ys;
        __syncthreads();
        // L0: 16 -> 64
        float a = tanh_f(dot16((const float4*)s_in, w0v, bs0));
        s_hA[j] = a;
        __syncthreads();
        // L1: 64 -> 64
        float a1 = tanh_f(dot64((const float4*)s_hA, w1v, bs1));
        s_hB[j] = a1;
        __syncthreads();
        // L2: 64 -> 64
        float a2 = tanh_f(dot64((const float4*)s_hB, w2v, bs2));
        s_hA[j] = a2;           // safe: L1's s_hA reads drained at the sync above
        __syncthreads();
        // L3: 64 -> 16, split-k over 4 lane-groups then butterfly-reduce
        float p = dot16((const float4*)s_hA + (j >> 4) * 4, w3v, 0.f);
        p += __shfl_xor(p, 16);
        p += __shfl_xor(p, 32);
        __syncthreads();        // protect s_hA/s_in before next call's writes
        return p + b3r;
    };

    // Tsit5 tableau (f32)
    const float A21 = 0.161f;
    const float A31 = -0.008480655492356989f, A32 = 0.335480655492357f;
    const float A41 = 2.8971530571054935f, A42 = -6.359448489975075f, A43 = 4.3622954328695815f;
    const float A51 = 5.325864828439257f, A52 = -11.748883564062828f, A53 = 7.4955393428898365f, A54 = -0.09249506636175525f;
    const float A61 = 5.86145544294642f, A62 = -12.92096931784711f, A63 = 8.159367898576159f, A64 = -0.071584973281401f, A65 = -0.028269050394068383f;
    const float B1 = 0.09646076681806523f, B2 = 0.01f, B3 = 0.4798896504144996f,
                B4 = 1.379008574103742f, B5 = -3.290069515436081f, B6 = 2.324710524099774f;
    const float E1 = -0.00178001105222577714f, E2 = -0.0008164344596567469f,
                E3 = 0.007880878010261995f, E4 = -0.1447110071732629f,
                E5 = 0.5823571654525552f, E6 = -0.45808210592918697f, E7 = 0.015151515151515152f;
    const float TDONE = (float)(1.0 - 1e-7);

    float y = 0.0f;                       // h0 = zeros (replicated component i16)

    #pragma unroll 1
    for (int l = 0; l < LSEQ; ++l) {
        // ---------------- adaptive Tsit5 on [0,1], dt0 = 1 ----------------
        float t = 0.f, dt = 1.f;
        #pragma unroll 1
        for (int it = 0; it < 12; ++it) {
            if (t >= TDONE) break;        // identical to reference's frozen no-op iters
            float dtc = fminf(dt, 1.0f - t);
            float k1 = mlp(y);
            float k2 = mlp(fmaf(dtc, A21 * k1, y));
            float k3 = mlp(fmaf(dtc, A31*k1 + A32*k2, y));
            float k4 = mlp(fmaf(dtc, A41*k1 + A42*k2 + A43*k3, y));
            float k5 = mlp(fmaf(dtc, A51*k1 + A52*k2 + A53*k3 + A54*k4, y));
            float k6 = mlp(fmaf(dtc, A61*k1 + A62*k2 + A63*k3 + A64*k4 + A65*k5, y));
            float ynew = fmaf(dtc, B1*k1 + B2*k2 + B3*k3 + B4*k4 + B5*k5 + B6*k6, y);
            float k7 = mlp(ynew);
            float yerr = dtc * (E1*k1 + E2*k2 + E3*k3 + E4*k4 + E5*k5 + E6*k6 + E7*k7);
            float sc = fmaf(0.01f, fmaxf(fabsf(y), fabsf(ynew)), 1e-4f);
            float e = yerr / sc;          // keep IEEE: feeds the accept branch
            float e2 = e * e;
            e2 += __shfl_xor(e2, 1); e2 += __shfl_xor(e2, 2);
            e2 += __shfl_xor(e2, 4); e2 += __shfl_xor(e2, 8);
            float err = sqrtf(e2 * 0.0625f);       // mean over 16 comps, sqrt
            if (err <= 1.0f) { y = ynew; t += dtc; }
            // err^(-0.2): err > 0 guaranteed by the 1e-10 clamp
            float fac = 0.9f * exp2f(-0.2f * log2f(fmaxf(err, 1e-10f)));
            fac = fminf(fmaxf(fac, 0.2f), 10.0f);
            dt = dtc * fac;
        }
        // ---------------- GRU observation update ----------------
        float x0 = s_x[2*l], x1 = s_x[2*l + 1];
        if (j < 16) s_in[j] = y;
        __syncthreads();
        float hg = dot16((const float4*)s_in, whv, 0.f);
        float ig = fmaf(wih0, x0, fmaf(wih1, x1, bihj));
        if (j < 48) { s_ig[j] = ig; s_hg[j] = hg; }
        __syncthreads();
        float ir = s_ig[i16], iz = s_ig[16+i16], in_ = s_ig[32+i16];
        float hr = s_hg[i16], hz = s_hg[16+i16], hn = s_hg[32+i16];
        float r = sigm_f(ir + hr);
        float z = sigm_f(iz + hz);
        float n = tanh_f(fmaf(r, hn + bnr, in_));
        y = n + z * (y - n);
        __syncthreads();    // protect s_in/s_ig/s_hg before next iteration's writes
    }

    // ---------------- projection: out[b] = Wp . h + bp ----------------
    float pv = y * wpr;
    pv += __shfl_xor(pv, 1); pv += __shfl_xor(pv, 2);
    pv += __shfl_xor(pv, 4); pv += __shfl_xor(pv, 8);
    if (j == 0) out[b] = pv + bp[0];
}

extern "C" void kernel_launch(void* const* d_in, const int* in_sizes, int n_in,
                              void* d_out, int out_size, void* d_ws, size_t ws_size,
                              hipStream_t stream)
{
    odern_kernel<<<dim3(512), dim3(64), 0, stream>>>(
        (const float*)d_in[0],
        (const float*)d_in[1],  (const float*)d_in[2],
        (const float*)d_in[3],  (const float*)d_in[4],
        (const float*)d_in[5],  (const float*)d_in[6],
        (const float*)d_in[7],  (const float*)d_in[8],
        (const float*)d_in[9],  (const float*)d_in[10],
        (const float*)d_in[11], (const float*)d_in[12],
        (const float*)d_in[13], (const float*)d_in[14],
        (float*)d_out);
}